// Round 4
// baseline (318.266 us; speedup 1.0000x reference)
//
#include <hip/hip_runtime.h>

// Problem constants
#define NB 4
#define NC 32
#define NPIX 262144   // 512*512
#define NI 8
#define NE 512
#define FEPS 1e-12f

// Workspace layout (float offsets)
#define WS_SUMS   0        // [4][8][32] = 1024
#define WS_CNT    1024     // [32]
#define WS_HINGE  1056     // [32]
#define WS_EDGE   1088     // [1]
#define WS_ZERO_N 1089
#define WS_SEL    2048     // int [4*8*512] = 16384
#define WS_EB     20480    // bf16 [4*4096*32] = 524288 shorts
#define WS_SQ     544768   // [16384]

typedef __bf16 bf16x8 __attribute__((ext_vector_type(8)));
typedef float  f32x4  __attribute__((ext_vector_type(4)));

static __device__ __forceinline__ unsigned short f2bf(float x) {
    unsigned u = __builtin_bit_cast(unsigned, x);
    u += 0x7FFF + ((u >> 16) & 1);          // RNE
    return (unsigned short)(u >> 16);
}

__global__ __launch_bounds__(256) void k_zero(float* __restrict__ ws) {
    int i = blockIdx.x * 256 + threadIdx.x;
    if (i < WS_ZERO_N) ws[i] = 0.f;
}

// Pass 1: segment sums + counts. 2048 blocks: (b, chunk of 1024 px, 16-ch half).
// Wave owns 4 channels (32 AGPR acc) -> ~5 waves/SIMD; A/B pipelined loads.
__global__ __launch_bounds__(256, 4) void k_seg_sums(const float* __restrict__ feat,
                                                     const int* __restrict__ lab,
                                                     float* __restrict__ sums,
                                                     float* __restrict__ cnts) {
    int tid = threadIdx.x;
    int lane = tid & 63, w = tid >> 6;
    int blk = blockIdx.x;
    int b = blk >> 9, rem = blk & 511;
    int cb = rem >> 1, h = rem & 1;
    int ch0 = h * 16 + w * 4;
    const float* fb = feat + ((size_t)b * NC + ch0) * NPIX + cb * 1024;
    const int*   lb = lab + (size_t)b * NPIX + cb * 1024;
    bool docnt = (w == 0) && (h == 0);

    float r[32];
#pragma unroll
    for (int k = 0; k < 32; k++) r[k] = 0.f;
    float cnt[8] = {0.f, 0.f, 0.f, 0.f, 0.f, 0.f, 0.f, 0.f};

#define ACC_ELEM(lx, v0, v1, v2, v3)                         \
    do {                                                     \
        _Pragma("unroll")                                    \
        for (int bin = 0; bin < 8; ++bin) {                  \
            float mk = ((lx) == bin) ? 1.f : 0.f;            \
            if (docnt) cnt[bin] += mk;                       \
            r[bin]      += mk * (v0);                        \
            r[8 + bin]  += mk * (v1);                        \
            r[16 + bin] += mk * (v2);                        \
            r[24 + bin] += mk * (v3);                        \
        }                                                    \
    } while (0)

    int4   lvA = *(const int4*)(lb + lane * 4);
    float4 fA0 = *(const float4*)(fb + 0 * (size_t)NPIX + lane * 4);
    float4 fA1 = *(const float4*)(fb + 1 * (size_t)NPIX + lane * 4);
    float4 fA2 = *(const float4*)(fb + 2 * (size_t)NPIX + lane * 4);
    float4 fA3 = *(const float4*)(fb + 3 * (size_t)NPIX + lane * 4);

#pragma unroll
    for (int g = 0; g < 4; g++) {
        int4 lvC = lvA;
        float4 c0 = fA0, c1 = fA1, c2 = fA2, c3 = fA3;
        if (g < 3) {
            int idx = (g + 1) * 256 + lane * 4;
            lvA = *(const int4*)(lb + idx);
            fA0 = *(const float4*)(fb + 0 * (size_t)NPIX + idx);
            fA1 = *(const float4*)(fb + 1 * (size_t)NPIX + idx);
            fA2 = *(const float4*)(fb + 2 * (size_t)NPIX + idx);
            fA3 = *(const float4*)(fb + 3 * (size_t)NPIX + idx);
        }
        ACC_ELEM(lvC.x, c0.x, c1.x, c2.x, c3.x);
        ACC_ELEM(lvC.y, c0.y, c1.y, c2.y, c3.y);
        ACC_ELEM(lvC.z, c0.z, c1.z, c2.z, c3.z);
        ACC_ELEM(lvC.w, c0.w, c1.w, c2.w, c3.w);
    }
#undef ACC_ELEM

    // fold 32 accs across 64 lanes: bit-32 pre-fold, then 32-wide halving.
#pragma unroll
    for (int k = 0; k < 32; k++) r[k] += __shfl_xor(r[k], 32);
#pragma unroll
    for (int half = 16; half >= 1; half >>= 1) {
#pragma unroll
        for (int k = 0; k < half; k++) {
            float t0 = __shfl_xor(r[k], half);
            float t1 = __shfl_xor(r[k + half], half);
            r[k] = (lane & half) ? (r[k + half] + t1) : (r[k] + t0);
        }
    }
    if (lane < 32)
        atomicAdd(&sums[((size_t)b * NI + (lane & 7)) * NC + ch0 + (lane >> 3)], r[0]);

    if (docnt) {
#pragma unroll
        for (int m = 8; m <= 32; m <<= 1) {
#pragma unroll
            for (int bin = 0; bin < 8; bin++) cnt[bin] += __shfl_xor(cnt[bin], m);
        }
#pragma unroll
        for (int half = 4; half >= 1; half >>= 1) {
#pragma unroll
            for (int k = 0; k < half; k++) {
                float t0 = __shfl_xor(cnt[k], half);
                float t1 = __shfl_xor(cnt[k + half], half);
                cnt[k] = (lane & half) ? (cnt[k + half] + t1) : (cnt[k] + t0);
            }
        }
        if (lane < 8) atomicAdd(&cnts[b * NI + lane], cnt[0]);
    }
}

// Pass 2: per-pixel ||f - mu_lab||, hinge^2, binned. Double-buffered loads.
__global__ __launch_bounds__(256, 4) void k_var(const float* __restrict__ feat,
                                                const int* __restrict__ lab,
                                                const float* __restrict__ sums,
                                                const float* __restrict__ cnts,
                                                float* __restrict__ hinge) {
    __shared__ float mlds[NI][33];
    __shared__ float hred[4][8];
    int tid = threadIdx.x;
    int lane = tid & 63, w = tid >> 6;
    int b = blockIdx.x >> 8, cb = blockIdx.x & 255;
    {
        int i = tid >> 5, c = tid & 31;
        mlds[i][c] = sums[(b * NI + i) * NC + c] / cnts[b * NI + i];
    }
    __syncthreads();

    int idx = tid * 4;
    int4 lv = *(const int4*)(lab + (size_t)b * NPIX + cb * 1024 + idx);
    const float* fb = feat + (size_t)b * NC * NPIX + cb * 1024 + idx;
    float ax = 0.f, ay = 0.f, az = 0.f, aw = 0.f;

    float4 FA[8], FB[8];
#define LOADF(BUF, CC)                                                          \
    do {                                                                        \
        _Pragma("unroll")                                                       \
        for (int u = 0; u < 8; ++u)                                             \
            BUF[u] = *(const float4*)(fb + (size_t)((CC) + u) * NPIX);          \
    } while (0)
#define CONSUME(BUF, CC)                                                        \
    do {                                                                        \
        _Pragma("unroll")                                                       \
        for (int u = 0; u < 8; ++u) {                                           \
            int c = (CC) + u;                                                   \
            float d;                                                            \
            d = BUF[u].x - mlds[lv.x][c]; ax += d * d;                          \
            d = BUF[u].y - mlds[lv.y][c]; ay += d * d;                          \
            d = BUF[u].z - mlds[lv.z][c]; az += d * d;                          \
            d = BUF[u].w - mlds[lv.w][c]; aw += d * d;                          \
        }                                                                       \
    } while (0)

    LOADF(FA, 0);
    LOADF(FB, 8);  CONSUME(FA, 0);
    LOADF(FA, 16); CONSUME(FB, 8);
    LOADF(FB, 24); CONSUME(FA, 16);
    CONSUME(FB, 24);
#undef LOADF
#undef CONSUME

    float t;
    t = fmaxf(sqrtf(ax + FEPS) - 0.5f, 0.f); float hx = t * t;
    t = fmaxf(sqrtf(ay + FEPS) - 0.5f, 0.f); float hy = t * t;
    t = fmaxf(sqrtf(az + FEPS) - 0.5f, 0.f); float hz = t * t;
    t = fmaxf(sqrtf(aw + FEPS) - 0.5f, 0.f); float hw = t * t;

    float hacc[8];
#pragma unroll
    for (int bin = 0; bin < 8; bin++)
        hacc[bin] = ((lv.x == bin) ? hx : 0.f) + ((lv.y == bin) ? hy : 0.f)
                  + ((lv.z == bin) ? hz : 0.f) + ((lv.w == bin) ? hw : 0.f);
#pragma unroll
    for (int m = 8; m <= 32; m <<= 1) {
#pragma unroll
        for (int bin = 0; bin < 8; bin++) hacc[bin] += __shfl_xor(hacc[bin], m);
    }
#pragma unroll
    for (int half = 4; half >= 1; half >>= 1) {
#pragma unroll
        for (int k = 0; k < half; k++) {
            float t0 = __shfl_xor(hacc[k], half);
            float t1 = __shfl_xor(hacc[k + half], half);
            hacc[k] = (lane & half) ? (hacc[k + half] + t1) : (hacc[k] + t0);
        }
    }
    if (lane < 8) hred[w][lane] = hacc[0];
    __syncthreads();
    if (tid < 8)
        atomicAdd(&hinge[b * NI + tid],
                  hred[0][tid] + hred[1][tid] + hred[2][tid] + hred[3][tid]);
}

// Ordered "first 512 pixels with labelEdges==i" per (b,i). One wave per pair.
__global__ __launch_bounds__(64) void k_sel(const int* __restrict__ le, int* __restrict__ sel) {
    int inst = blockIdx.x & 7;
    int b = blockIdx.x >> 3;
    int lane = threadIdx.x;
    const int* lp = le + (size_t)b * NPIX;
    int* sp = sel + blockIdx.x * NE;
    int s = 0;
    for (int base = 0; base < NPIX && s < NE; base += 256) {
        int4 l = *(const int4*)(lp + base + lane * 4);
        int m0 = (l.x == inst), m1 = (l.y == inst), m2 = (l.z == inst), m3 = (l.w == inst);
        int cnt = m0 + m1 + m2 + m3;
        int incl = cnt;
#pragma unroll
        for (int off = 1; off < 64; off <<= 1) {
            int t = __shfl_up(incl, off);
            if (lane >= off) incl += t;
        }
        int r = incl - cnt;
        int pbase = base + lane * 4;
        if (m0) { if (s + r < NE) sp[s + r] = pbase + 0; r++; }
        if (m1) { if (s + r < NE) sp[s + r] = pbase + 1; r++; }
        if (m2) { if (s + r < NE) sp[s + r] = pbase + 2; r++; }
        if (m3) { if (s + r < NE) sp[s + r] = pbase + 3; r++; }
        s += __shfl(incl, 63);
    }
    for (int idx = s + lane; idx < NE; idx += 64) sp[idx] = 0;  // safety, never expected
}

// Gather edge rows -> bf16 [16384][32] + f32 sq norms. 256 blocks,
// thread = (row, 8-channel quad): 8 independent scalar loads, one int4 store.
__global__ __launch_bounds__(256) void k_gather(const float* __restrict__ feat,
                                                const int* __restrict__ sel,
                                                short* __restrict__ ebh,
                                                float* __restrict__ sq) {
    int oct = blockIdx.x;         // 0..7
    int bi = blockIdx.y;          // 0..31 = b*8+i
    int b = bi >> 3;
    int tid = threadIdx.x;
    int rrel = tid >> 2, qc = tid & 3;
    int r = bi * NE + oct * 64 + rrel;
    int p = sel[r];
    const float* fp = feat + (size_t)b * NC * NPIX + p;
    int c0 = qc * 8;
    float s = 0.f;
    int pk[4];
#pragma unroll
    for (int j = 0; j < 4; j++) {
        float v0 = fp[(size_t)(c0 + 2 * j) * NPIX];
        float v1 = fp[(size_t)(c0 + 2 * j + 1) * NPIX];
        s += v0 * v0 + v1 * v1;
        pk[j] = (unsigned)f2bf(v0) | ((unsigned)f2bf(v1) << 16);
    }
    *(int4*)(ebh + (size_t)r * NC + c0) = make_int4(pk[0], pk[1], pk[2], pk[3]);
    s += __shfl_xor(s, 1);
    s += __shfl_xor(s, 2);
    if (qc == 0) sq[r] = s;
}

// Edge pair loss via MFMA (16x16x32 bf16, K=32=NC in one instruction).
__global__ __launch_bounds__(256) void k_edge(const short* __restrict__ ebh,
                                              const float* __restrict__ sq,
                                              float* __restrict__ edge_acc) {
    __shared__ float sqa[128], sqb[128];
    __shared__ float wsum[4];
    int tid = threadIdx.x;
    int lane = tid & 63, w = tid >> 6;
    int ti = blockIdx.x >> 2, tj = blockIdx.x & 3;
    int q = blockIdx.y;       // 0..27
    int b = blockIdx.z;
    int pi = 0, pj = 0, k = q;
    for (int i = 0; i < 8; i++) { int row = 7 - i; if (k < row) { pi = i; pj = i + 1 + k; break; } k -= row; }
    int base_a = b * 4096 + pi * NE + ti * 128;
    int base_b = b * 4096 + pj * NE + tj * 128;

    if (tid < 128) sqa[tid] = sq[base_a + tid];
    else sqb[tid - 128] = sq[base_b + tid - 128];
    __syncthreads();

    int lrow = lane & 15;
    int lk = (lane >> 4) * 8;

    bf16x8 a[2];
#pragma unroll
    for (int u = 0; u < 2; u++)
        a[u] = *(const bf16x8*)(ebh + (size_t)(base_a + w * 32 + u * 16 + lrow) * NC + lk);
    bf16x8 bb[8];
#pragma unroll
    for (int v = 0; v < 8; v++)
        bb[v] = *(const bf16x8*)(ebh + (size_t)(base_b + v * 16 + lrow) * NC + lk);

    f32x4 acc[2][8];
#pragma unroll
    for (int u = 0; u < 2; u++)
#pragma unroll
        for (int v = 0; v < 8; v++) acc[u][v] = (f32x4){0.f, 0.f, 0.f, 0.f};

#pragma unroll
    for (int u = 0; u < 2; u++)
#pragma unroll
        for (int v = 0; v < 8; v++)
            acc[u][v] = __builtin_amdgcn_mfma_f32_16x16x32_bf16(a[u], bb[v], acc[u][v], 0, 0, 0);

    // C/D layout [m89]: col=lane&15, row=(lane>>4)*4+reg
    float lsum = 0.f;
    int orow0 = w * 32 + (lane >> 4) * 4;
    int ocol = lane & 15;
#pragma unroll
    for (int u = 0; u < 2; u++) {
#pragma unroll
        for (int v = 0; v < 8; v++) {
            float sb = sqb[v * 16 + ocol];
#pragma unroll
            for (int rg = 0; rg < 4; rg++) {
                float d2 = sqa[orow0 + u * 16 + rg] + sb - 2.f * acc[u][v][rg];
                float pd = sqrtf(fmaxf(d2, 0.f) + FEPS);
                float t = 2.f - pd;                  // 2*(DD-DV)
                if (t > 0.f) lsum += t * t;
            }
        }
    }
#pragma unroll
    for (int off = 32; off > 0; off >>= 1) lsum += __shfl_xor(lsum, off);
    if (lane == 0) wsum[w] = lsum;
    __syncthreads();
    if (tid == 0) atomicAdd(edge_acc, wsum[0] + wsum[1] + wsum[2] + wsum[3]);
}

// Final combine: var, dist, edge, reg, total -> d_out[5]
__global__ __launch_bounds__(256) void k_final(const float* __restrict__ sums,
                                               const float* __restrict__ cnts,
                                               const float* __restrict__ hinge,
                                               const float* __restrict__ edge_acc,
                                               float* __restrict__ out) {
    __shared__ float m[NB * NI * NC];
    __shared__ float accs[3];   // var, dist, reg
    int tid = threadIdx.x;
    if (tid < 3) accs[tid] = 0.f;
    for (int i = tid; i < NB * NI * NC; i += 256) m[i] = sums[i] / cnts[i >> 5];
    __syncthreads();

    float var_p = 0.f, dist_p = 0.f, reg_p = 0.f;
    if (tid < 32) {   // (b, i)
        var_p = hinge[tid] / cnts[tid] * (1.f / 8.f);
        const float* mm = &m[tid * NC];
        float s = 0.f;
        for (int c = 0; c < NC; c++) s += mm[c] * mm[c];
        reg_p = sqrtf(s + FEPS) * (0.001f / 8.f);   // DELTA / N
    }
    if (tid < NB * 28) {
        int b = tid / 28, q = tid % 28;
        int pi = 0, pj = 0, k = q;
        for (int i = 0; i < 8; i++) { int row = 7 - i; if (k < row) { pi = i; pj = i + 1 + k; break; } k -= row; }
        const float* ma = &m[(b * NI + pi) * NC];
        const float* mb = &m[(b * NI + pj) * NC];
        float s = 0.f;
        for (int c = 0; c < NC; c++) { float d = ma[c] - mb[c]; s += d * d; }
        float dm = sqrtf(s + FEPS);
        float t = fmaxf(3.0f - dm, 0.f);   // 2*DD - dm
        dist_p = t * t * (1.f / 56.f);
    }
    atomicAdd(&accs[0], var_p);
    atomicAdd(&accs[1], dist_p);
    atomicAdd(&accs[2], reg_p);
    __syncthreads();
    if (tid == 0) {
        float var = accs[0], dist = accs[1], reg = accs[2];
        float edge = edge_acc[0] * (1.f / (512.f * 512.f * 56.f));
        out[0] = var + dist + edge + reg;
        out[1] = var;
        out[2] = dist;
        out[3] = edge;
        out[4] = reg;
    }
}

extern "C" void kernel_launch(void* const* d_in, const int* in_sizes, int n_in,
                              void* d_out, int out_size, void* d_ws, size_t ws_size,
                              hipStream_t stream) {
    const float* feat   = (const float*)d_in[0];
    const int*   labels = (const int*)d_in[1];
    const int*   le     = (const int*)d_in[2];
    float* out = (float*)d_out;
    float* ws  = (float*)d_ws;

    float* sums  = ws + WS_SUMS;
    float* cnts  = ws + WS_CNT;
    float* hinge = ws + WS_HINGE;
    float* edge  = ws + WS_EDGE;
    int*   sel   = (int*)(ws + WS_SEL);
    short* ebh   = (short*)(ws + WS_EB);
    float* sq    = ws + WS_SQ;

    hipLaunchKernelGGL(k_zero,     dim3(5),           dim3(256), 0, stream, ws);
    hipLaunchKernelGGL(k_seg_sums, dim3(2048),        dim3(256), 0, stream, feat, labels, sums, cnts);
    hipLaunchKernelGGL(k_var,      dim3(1024),        dim3(256), 0, stream, feat, labels, sums, cnts, hinge);
    hipLaunchKernelGGL(k_sel,      dim3(32),          dim3(64),  0, stream, le, sel);
    hipLaunchKernelGGL(k_gather,   dim3(8, 32),       dim3(256), 0, stream, feat, sel, ebh, sq);
    hipLaunchKernelGGL(k_edge,     dim3(16, 28, 4),   dim3(256), 0, stream, ebh, sq, edge);
    hipLaunchKernelGGL(k_final,    dim3(1),           dim3(256), 0, stream, sums, cnts, hinge, edge, out);
}

// Round 5
// 286.896 us; speedup vs baseline: 1.1093x; 1.1093x over previous
//
#include <hip/hip_runtime.h>

// Problem constants
#define NB 4
#define NC 32
#define NPIX 262144   // 512*512
#define NI 8
#define NE 512
#define FEPS 1e-12f
#define NSH 8         // atomic shards for psums

// Workspace layout (float offsets)
#define WS_SUMS   0        // unused now (kept for clarity)
#define WS_HINGE  1056     // [32]
#define WS_EDGE   1088     // [1]
#define WS_PSUM   1152     // [8 shards][4*8*32] = 8192
#define WS_PCNT   9344     // [8 shards][32] = 256
#define WS_ZERO_N 9600
#define WS_SEL    10240    // int [4*8*512] = 16384
#define WS_EB     28672    // bf16 [16384][32] = 524288 shorts = 262144 floats
#define WS_SQ     294912   // [16384]

typedef __bf16 bf16x8 __attribute__((ext_vector_type(8)));
typedef float  f32x4  __attribute__((ext_vector_type(4)));

static __device__ __forceinline__ unsigned short f2bf(float x) {
    unsigned u = __builtin_bit_cast(unsigned, x);
    u += 0x7FFF + ((u >> 16) & 1);          // RNE
    return (unsigned short)(u >> 16);
}

__global__ __launch_bounds__(256) void k_zero(float* __restrict__ ws) {
    int i = blockIdx.x * 256 + threadIdx.x;
    if (i < WS_ZERO_N) ws[i] = 0.f;
}

// Pass 1 via MFMA: D[bin][ch] = sum_px mask[bin][px] * feat[px][ch].
// Grid 2048 = 4 img x 512 chunks(512 px). Block 256 = 4 waves; wave w owns
// px [w*128, w*128+128) in 4 iters of 32 px; each wave covers all 32 ch
// (2 MFMAs/iter). Accumulator = 8 f32 regs. Masks exact in bf16; feat RNE->bf16.
__global__ __launch_bounds__(256, 4) void k_seg_sums(const float* __restrict__ feat,
                                                     const int* __restrict__ lab,
                                                     float* __restrict__ psums,
                                                     float* __restrict__ pcnts) {
    __shared__ float sred[4][NI][33];
    __shared__ float cred[4][NI];
    int tid = threadIdx.x, lane = tid & 63, w = tid >> 6;
    int blk = blockIdx.x;
    int b = blk >> 9, chunk = blk & 511;
    int p0 = chunk * 512 + w * 128;
    int kg = lane >> 4, rc = lane & 15;
    const int* lb = lab + (size_t)b * NPIX;
    const float* f0 = feat + ((size_t)b * NC + rc) * NPIX;        // ch = rc
    const float* f1 = feat + ((size_t)b * NC + 16 + rc) * NPIX;   // ch = 16+rc

    f32x4 acc0 = {0.f, 0.f, 0.f, 0.f}, acc1 = {0.f, 0.f, 0.f, 0.f};
    float cnt = 0.f;

#pragma unroll 2
    for (int it = 0; it < 4; it++) {
        int p = p0 + it * 32 + kg * 8;
        int4 la = *(const int4*)(lb + p);
        int4 lc = *(const int4*)(lb + p + 4);
        float4 a0 = *(const float4*)(f0 + p);
        float4 a1 = *(const float4*)(f0 + p + 4);
        float4 b0 = *(const float4*)(f1 + p);
        float4 b1 = *(const float4*)(f1 + p + 4);

        uint4 mu;
        mu.x = (la.x == rc ? 0x3F80u : 0u) | (la.y == rc ? 0x3F800000u : 0u);
        mu.y = (la.z == rc ? 0x3F80u : 0u) | (la.w == rc ? 0x3F800000u : 0u);
        mu.z = (lc.x == rc ? 0x3F80u : 0u) | (lc.y == rc ? 0x3F800000u : 0u);
        mu.w = (lc.z == rc ? 0x3F80u : 0u) | (lc.w == rc ? 0x3F800000u : 0u);
        cnt += (float)((la.x == rc) + (la.y == rc) + (la.z == rc) + (la.w == rc)
                     + (lc.x == rc) + (lc.y == rc) + (lc.z == rc) + (lc.w == rc));
        bf16x8 af = __builtin_bit_cast(bf16x8, mu);
        bf16x8 bf0 = {(__bf16)a0.x, (__bf16)a0.y, (__bf16)a0.z, (__bf16)a0.w,
                      (__bf16)a1.x, (__bf16)a1.y, (__bf16)a1.z, (__bf16)a1.w};
        bf16x8 bf1 = {(__bf16)b0.x, (__bf16)b0.y, (__bf16)b0.z, (__bf16)b0.w,
                      (__bf16)b1.x, (__bf16)b1.y, (__bf16)b1.z, (__bf16)b1.w};
        acc0 = __builtin_amdgcn_mfma_f32_16x16x32_bf16(af, bf0, acc0, 0, 0, 0);
        acc1 = __builtin_amdgcn_mfma_f32_16x16x32_bf16(af, bf1, acc1, 0, 0, 0);
    }

    // D layout: col=lane&15, row=(lane>>4)*4+reg. Bins = rows 0-7 -> lanes 0-31.
    if (lane < 32) {
#pragma unroll
        for (int rg = 0; rg < 4; rg++) {
            int row = (lane >> 4) * 4 + rg;
            sred[w][row][rc] = acc0[rg];
            sred[w][row][16 + rc] = acc1[rg];
        }
    }
    cnt += __shfl_xor(cnt, 16);
    cnt += __shfl_xor(cnt, 32);
    if (lane < 8) cred[w][lane] = cnt;
    __syncthreads();

    int sh = blk & (NSH - 1);
    {
        int bin = tid >> 5, ch = tid & 31;
        float s = sred[0][bin][ch] + sred[1][bin][ch] + sred[2][bin][ch] + sred[3][bin][ch];
        atomicAdd(&psums[sh * (NB * NI * NC) + ((size_t)b * NI + bin) * NC + ch], s);
    }
    if (tid < 8)
        atomicAdd(&pcnts[sh * (NB * NI) + b * NI + tid],
                  cred[0][tid] + cred[1][tid] + cred[2][tid] + cred[3][tid]);
}

// Pass 2: 2 px/thread, float2 loads, full-unrolled 32-ch loop, means in LDS.
// Grid 2048 = 4 img x 512 chunks(512 px).
__global__ __launch_bounds__(256, 4) void k_var(const float* __restrict__ feat,
                                                const int* __restrict__ lab,
                                                const float* __restrict__ psums,
                                                const float* __restrict__ pcnts,
                                                float* __restrict__ hinge) {
    __shared__ float mlds[NI][33];
    __shared__ float hred[4][8];
    int tid = threadIdx.x, lane = tid & 63, w = tid >> 6;
    int blk = blockIdx.x;
    int b = blk >> 9, chunk = blk & 511;
    {
        int bin = tid >> 5, ch = tid & 31;
        float s = 0.f, c = 0.f;
#pragma unroll
        for (int sh = 0; sh < NSH; sh++) {
            s += psums[sh * (NB * NI * NC) + ((size_t)b * NI + bin) * NC + ch];
            c += pcnts[sh * (NB * NI) + b * NI + bin];
        }
        mlds[bin][ch] = s / c;
    }
    __syncthreads();

    int p0 = chunk * 512 + tid * 2;
    int2 lv = *(const int2*)(lab + (size_t)b * NPIX + p0);
    const float* fb = feat + (size_t)b * NC * NPIX + p0;
    float a0 = 0.f, a1 = 0.f;
#pragma unroll
    for (int c = 0; c < NC; c++) {
        float2 f = *(const float2*)(fb + (size_t)c * NPIX);
        float d0 = f.x - mlds[lv.x][c]; a0 += d0 * d0;
        float d1 = f.y - mlds[lv.y][c]; a1 += d1 * d1;
    }
    float t;
    t = fmaxf(sqrtf(a0 + FEPS) - 0.5f, 0.f); float h0 = t * t;
    t = fmaxf(sqrtf(a1 + FEPS) - 0.5f, 0.f); float h1 = t * t;

    float hacc[8];
#pragma unroll
    for (int bin = 0; bin < 8; bin++)
        hacc[bin] = ((lv.x == bin) ? h0 : 0.f) + ((lv.y == bin) ? h1 : 0.f);
#pragma unroll
    for (int m = 8; m <= 32; m <<= 1) {
#pragma unroll
        for (int bin = 0; bin < 8; bin++) hacc[bin] += __shfl_xor(hacc[bin], m);
    }
#pragma unroll
    for (int half = 4; half >= 1; half >>= 1) {
#pragma unroll
        for (int k = 0; k < half; k++) {
            float t0 = __shfl_xor(hacc[k], half);
            float t1 = __shfl_xor(hacc[k + half], half);
            hacc[k] = (lane & half) ? (hacc[k + half] + t1) : (hacc[k] + t0);
        }
    }
    if (lane < 8) hred[w][lane] = hacc[0];
    __syncthreads();
    if (tid < 8)
        atomicAdd(&hinge[b * NI + tid],
                  hred[0][tid] + hred[1][tid] + hred[2][tid] + hred[3][tid]);
}

// Ordered "first 512 pixels with labelEdges==i" per (b,i). One wave per pair.
__global__ __launch_bounds__(64) void k_sel(const int* __restrict__ le, int* __restrict__ sel) {
    int inst = blockIdx.x & 7;
    int b = blockIdx.x >> 3;
    int lane = threadIdx.x;
    const int* lp = le + (size_t)b * NPIX;
    int* sp = sel + blockIdx.x * NE;
    int s = 0;
    for (int base = 0; base < NPIX && s < NE; base += 256) {
        int4 l = *(const int4*)(lp + base + lane * 4);
        int m0 = (l.x == inst), m1 = (l.y == inst), m2 = (l.z == inst), m3 = (l.w == inst);
        int cnt = m0 + m1 + m2 + m3;
        int incl = cnt;
#pragma unroll
        for (int off = 1; off < 64; off <<= 1) {
            int t = __shfl_up(incl, off);
            if (lane >= off) incl += t;
        }
        int r = incl - cnt;
        int pbase = base + lane * 4;
        if (m0) { if (s + r < NE) sp[s + r] = pbase + 0; r++; }
        if (m1) { if (s + r < NE) sp[s + r] = pbase + 1; r++; }
        if (m2) { if (s + r < NE) sp[s + r] = pbase + 2; r++; }
        if (m3) { if (s + r < NE) sp[s + r] = pbase + 3; r++; }
        s += __shfl(incl, 63);
    }
    for (int idx = s + lane; idx < NE; idx += 64) sp[idx] = 0;  // safety, never expected
}

// Gather edge rows -> bf16 [16384][32] + f32 sq norms.
__global__ __launch_bounds__(256) void k_gather(const float* __restrict__ feat,
                                                const int* __restrict__ sel,
                                                short* __restrict__ ebh,
                                                float* __restrict__ sq) {
    int oct = blockIdx.x;         // 0..7
    int bi = blockIdx.y;          // 0..31 = b*8+i
    int b = bi >> 3;
    int tid = threadIdx.x;
    int rrel = tid >> 2, qc = tid & 3;
    int r = bi * NE + oct * 64 + rrel;
    int p = sel[r];
    const float* fp = feat + (size_t)b * NC * NPIX + p;
    int c0 = qc * 8;
    float s = 0.f;
    int pk[4];
#pragma unroll
    for (int j = 0; j < 4; j++) {
        float v0 = fp[(size_t)(c0 + 2 * j) * NPIX];
        float v1 = fp[(size_t)(c0 + 2 * j + 1) * NPIX];
        s += v0 * v0 + v1 * v1;
        pk[j] = (unsigned)f2bf(v0) | ((unsigned)f2bf(v1) << 16);
    }
    *(int4*)(ebh + (size_t)r * NC + c0) = make_int4(pk[0], pk[1], pk[2], pk[3]);
    s += __shfl_xor(s, 1);
    s += __shfl_xor(s, 2);
    if (qc == 0) sq[r] = s;
}

// Edge pair loss via MFMA (16x16x32 bf16, K=32=NC in one instruction).
__global__ __launch_bounds__(256) void k_edge(const short* __restrict__ ebh,
                                              const float* __restrict__ sq,
                                              float* __restrict__ edge_acc) {
    __shared__ float sqa[128], sqb[128];
    __shared__ float wsum[4];
    int tid = threadIdx.x;
    int lane = tid & 63, w = tid >> 6;
    int ti = blockIdx.x >> 2, tj = blockIdx.x & 3;
    int q = blockIdx.y;       // 0..27
    int b = blockIdx.z;
    int pi = 0, pj = 0, k = q;
    for (int i = 0; i < 8; i++) { int row = 7 - i; if (k < row) { pi = i; pj = i + 1 + k; break; } k -= row; }
    int base_a = b * 4096 + pi * NE + ti * 128;
    int base_b = b * 4096 + pj * NE + tj * 128;

    if (tid < 128) sqa[tid] = sq[base_a + tid];
    else sqb[tid - 128] = sq[base_b + tid - 128];
    __syncthreads();

    int lrow = lane & 15;
    int lk = (lane >> 4) * 8;

    bf16x8 a[2];
#pragma unroll
    for (int u = 0; u < 2; u++)
        a[u] = *(const bf16x8*)(ebh + (size_t)(base_a + w * 32 + u * 16 + lrow) * NC + lk);
    bf16x8 bb[8];
#pragma unroll
    for (int v = 0; v < 8; v++)
        bb[v] = *(const bf16x8*)(ebh + (size_t)(base_b + v * 16 + lrow) * NC + lk);

    f32x4 acc[2][8];
#pragma unroll
    for (int u = 0; u < 2; u++)
#pragma unroll
        for (int v = 0; v < 8; v++) acc[u][v] = (f32x4){0.f, 0.f, 0.f, 0.f};

#pragma unroll
    for (int u = 0; u < 2; u++)
#pragma unroll
        for (int v = 0; v < 8; v++)
            acc[u][v] = __builtin_amdgcn_mfma_f32_16x16x32_bf16(a[u], bb[v], acc[u][v], 0, 0, 0);

    float lsum = 0.f;
    int orow0 = w * 32 + (lane >> 4) * 4;
    int ocol = lane & 15;
#pragma unroll
    for (int u = 0; u < 2; u++) {
#pragma unroll
        for (int v = 0; v < 8; v++) {
            float sb = sqb[v * 16 + ocol];
#pragma unroll
            for (int rg = 0; rg < 4; rg++) {
                float d2 = sqa[orow0 + u * 16 + rg] + sb - 2.f * acc[u][v][rg];
                float pd = sqrtf(fmaxf(d2, 0.f) + FEPS);
                float t = 2.f - pd;                  // 2*(DD-DV)
                if (t > 0.f) lsum += t * t;
            }
        }
    }
#pragma unroll
    for (int off = 32; off > 0; off >>= 1) lsum += __shfl_xor(lsum, off);
    if (lane == 0) wsum[w] = lsum;
    __syncthreads();
    if (tid == 0) atomicAdd(edge_acc, wsum[0] + wsum[1] + wsum[2] + wsum[3]);
}

// Final combine (sums/cnts reduced from shards here): var, dist, edge, reg, total.
__global__ __launch_bounds__(256) void k_final(const float* __restrict__ psums,
                                               const float* __restrict__ pcnts,
                                               const float* __restrict__ hinge,
                                               const float* __restrict__ edge_acc,
                                               float* __restrict__ out) {
    __shared__ float m[NB * NI * NC];
    __shared__ float cshr[NB * NI];
    __shared__ float accs[3];   // var, dist, reg
    int tid = threadIdx.x;
    if (tid < 3) accs[tid] = 0.f;
    if (tid < NB * NI) {
        float c = 0.f;
#pragma unroll
        for (int sh = 0; sh < NSH; sh++) c += pcnts[sh * (NB * NI) + tid];
        cshr[tid] = c;
    }
    __syncthreads();
    for (int i = tid; i < NB * NI * NC; i += 256) {
        float s = 0.f;
#pragma unroll
        for (int sh = 0; sh < NSH; sh++) s += psums[sh * (NB * NI * NC) + i];
        m[i] = s / cshr[i >> 5];
    }
    __syncthreads();

    float var_p = 0.f, dist_p = 0.f, reg_p = 0.f;
    if (tid < 32) {   // (b, i)
        var_p = hinge[tid] / cshr[tid] * (1.f / 8.f);
        const float* mm = &m[tid * NC];
        float s = 0.f;
        for (int c = 0; c < NC; c++) s += mm[c] * mm[c];
        reg_p = sqrtf(s + FEPS) * (0.001f / 8.f);   // DELTA / N
    }
    if (tid < NB * 28) {
        int b = tid / 28, q = tid % 28;
        int pi = 0, pj = 0, k = q;
        for (int i = 0; i < 8; i++) { int row = 7 - i; if (k < row) { pi = i; pj = i + 1 + k; break; } k -= row; }
        const float* ma = &m[(b * NI + pi) * NC];
        const float* mb = &m[(b * NI + pj) * NC];
        float s = 0.f;
        for (int c = 0; c < NC; c++) { float d = ma[c] - mb[c]; s += d * d; }
        float dm = sqrtf(s + FEPS);
        float t = fmaxf(3.0f - dm, 0.f);   // 2*DD - dm
        dist_p = t * t * (1.f / 56.f);
    }
    atomicAdd(&accs[0], var_p);
    atomicAdd(&accs[1], dist_p);
    atomicAdd(&accs[2], reg_p);
    __syncthreads();
    if (tid == 0) {
        float var = accs[0], dist = accs[1], reg = accs[2];
        float edge = edge_acc[0] * (1.f / (512.f * 512.f * 56.f));
        out[0] = var + dist + edge + reg;
        out[1] = var;
        out[2] = dist;
        out[3] = edge;
        out[4] = reg;
    }
}

extern "C" void kernel_launch(void* const* d_in, const int* in_sizes, int n_in,
                              void* d_out, int out_size, void* d_ws, size_t ws_size,
                              hipStream_t stream) {
    const float* feat   = (const float*)d_in[0];
    const int*   labels = (const int*)d_in[1];
    const int*   le     = (const int*)d_in[2];
    float* out = (float*)d_out;
    float* ws  = (float*)d_ws;

    float* hinge = ws + WS_HINGE;
    float* edge  = ws + WS_EDGE;
    float* psums = ws + WS_PSUM;
    float* pcnts = ws + WS_PCNT;
    int*   sel   = (int*)(ws + WS_SEL);
    short* ebh   = (short*)(ws + WS_EB);
    float* sq    = ws + WS_SQ;

    hipLaunchKernelGGL(k_zero,     dim3(38),          dim3(256), 0, stream, ws);
    hipLaunchKernelGGL(k_seg_sums, dim3(2048),        dim3(256), 0, stream, feat, labels, psums, pcnts);
    hipLaunchKernelGGL(k_var,      dim3(2048),        dim3(256), 0, stream, feat, labels, psums, pcnts, hinge);
    hipLaunchKernelGGL(k_sel,      dim3(32),          dim3(64),  0, stream, le, sel);
    hipLaunchKernelGGL(k_gather,   dim3(8, 32),       dim3(256), 0, stream, feat, sel, ebh, sq);
    hipLaunchKernelGGL(k_edge,     dim3(16, 28, 4),   dim3(256), 0, stream, ebh, sq, edge);
    hipLaunchKernelGGL(k_final,    dim3(1),           dim3(256), 0, stream, psums, pcnts, hinge, edge, out);
}